// Round 10
// baseline (487.354 us; speedup 1.0000x reference)
//
#include <hip/hip_runtime.h>
#include <hip/hip_fp16.h>

#define EMB_C 64
#define N_USER_C 100000
#define BROWS 256        // rows per bucket
#define BSHIFT 8
#define COLBITS 18       // col fits 18 bits (n_nodes <= 262144)
#define CHUNK 2048       // edges per binning workgroup (4x grid vs r9)
#define NBMAX 640        // max buckets supported

// ============================ CSR path kernels ============================

// x0h = fp16(concat(user_emb, item_emb)); zero bhist region.
__global__ __launch_bounds__(256) void fill_h_kernel(
        const float4* __restrict__ ue, const float4* __restrict__ ie,
        ushort4* __restrict__ x0, int4* __restrict__ zint,
        long long u4, long long t4, long long z4) {
    long long i = (long long)blockIdx.x * blockDim.x + threadIdx.x;
    if (i < t4) {
        float4 v = (i < u4) ? ue[i] : ie[i - u4];
        ushort4 h;
        h.x = __half_as_ushort(__float2half(v.x));
        h.y = __half_as_ushort(__float2half(v.y));
        h.z = __half_as_ushort(__float2half(v.z));
        h.w = __half_as_ushort(__float2half(v.w));
        x0[i] = h;
    }
    if (i < z4) zint[i] = make_int4(0, 0, 0, 0);
}

// Bucket-level histogram via per-WG LDS hist; <=nb global atomics per WG.
__global__ __launch_bounds__(256) void buckethist_kernel(
        const int* __restrict__ rows, int* __restrict__ bhist, int nnz, int nb) {
    __shared__ int hist[NBMAX];
    for (int b = threadIdx.x; b < nb; b += 256) hist[b] = 0;
    __syncthreads();
    const int c0 = blockIdx.x * CHUNK;
    for (int i = threadIdx.x; i < CHUNK; i += 256) {
        int e = c0 + i;
        if (e < nnz) atomicAdd(&hist[rows[e] >> BSHIFT], 1);
    }
    __syncthreads();
    for (int b = threadIdx.x; b < nb; b += 256)
        if (hist[b]) atomicAdd(&bhist[b], hist[b]);
}

// Single block: exclusive-scan bucket hist -> bbase & gcur; rp[n_nodes]=nnz.
__global__ __launch_bounds__(1024) void bucketscan_kernel(
        const int* __restrict__ bhist, int* __restrict__ bbase,
        int* __restrict__ gcur, int* __restrict__ rp,
        int nb, int nnz, int n_nodes) {
    __shared__ int sh[1024];
    int v = (threadIdx.x < nb) ? bhist[threadIdx.x] : 0;
    sh[threadIdx.x] = v;
    __syncthreads();
    for (int off = 1; off < 1024; off <<= 1) {
        int t = (threadIdx.x >= off) ? sh[threadIdx.x - off] : 0;
        __syncthreads();
        sh[threadIdx.x] += t;
        __syncthreads();
    }
    if (threadIdx.x < nb) {
        int excl = sh[threadIdx.x] - v;
        bbase[threadIdx.x] = excl;
        gcur[threadIdx.x]  = excl;
    }
    if (threadIdx.x == 0) { bbase[nb] = nnz; rp[n_nodes] = nnz; }
}

// Phase 1: bin edges by bucket. Payload {(row_low<<COLBITS)|col, val_bits}.
__global__ __launch_bounds__(256) void binscatter_kernel(
        const int* __restrict__ rows, const int* __restrict__ cols,
        const float* __restrict__ vals, int* __restrict__ gcur,
        int2* __restrict__ bin, int nnz, int nb) {
    __shared__ int hist[NBMAX];
    __shared__ int base[NBMAX];
    __shared__ int cur[NBMAX];
    const int c0 = blockIdx.x * CHUNK;
    for (int b = threadIdx.x; b < nb; b += 256) { hist[b] = 0; cur[b] = 0; }
    __syncthreads();
    for (int i = threadIdx.x; i < CHUNK; i += 256) {
        int e = c0 + i;
        if (e < nnz) atomicAdd(&hist[rows[e] >> BSHIFT], 1);
    }
    __syncthreads();
    for (int b = threadIdx.x; b < nb; b += 256)
        if (hist[b]) base[b] = atomicAdd(&gcur[b], hist[b]);
    __syncthreads();
    for (int i = threadIdx.x; i < CHUNK; i += 256) {
        int e = c0 + i;
        if (e >= nnz) break;
        int r = rows[e];
        int b = r >> BSHIFT;
        int k = atomicAdd(&cur[b], 1);
        bin[base[b] + k] = make_int2(((r & (BROWS - 1)) << COLBITS) | cols[e],
                                     __float_as_int(vals[e]));
    }
}

// Phase 2 (one WG of 512 per bucket): count rows in LDS, scan (256 lanes),
// WRITE rp for this bucket, then scatter edges into row order.
__global__ __launch_bounds__(512) void finscatter_kernel(
        const int2* __restrict__ bin, const int* __restrict__ bbase,
        int* __restrict__ rp, int2* __restrict__ sce, int n_nodes) {
    __shared__ int cnt[BROWS];
    __shared__ int sh[BROWS];
    __shared__ int cur[BROWS];
    const int row0 = blockIdx.x << BSHIFT;
    const int tid = threadIdx.x;
    if (tid < BROWS) cnt[tid] = 0;
    __syncthreads();
    const int bb = bbase[blockIdx.x];
    const int be = bbase[blockIdx.x + 1];
    for (int p = bb + tid; p < be; p += 512)
        atomicAdd(&cnt[bin[p].x >> COLBITS], 1);
    __syncthreads();
    int v = 0;
    if (tid < BROWS) { v = cnt[tid]; sh[tid] = v; }
    __syncthreads();
    for (int off = 1; off < BROWS; off <<= 1) {
        int t = (tid < BROWS && tid >= off) ? sh[tid - off] : 0;
        __syncthreads();
        if (tid < BROWS) sh[tid] += t;
        __syncthreads();
    }
    if (tid < BROWS) {
        int excl = sh[tid] - v;
        cur[tid] = excl;
        if (row0 + tid < n_nodes) rp[row0 + tid] = bb + excl;   // coalesced rp
    }
    __syncthreads();
    for (int p = bb + tid; p < be; p += 512) {
        int2 e = bin[p];
        int rl = e.x >> COLBITS;
        int k = atomicAdd(&cur[rl], 1);
        sce[bb + k] = make_int2(e.x & ((1 << COLBITS) - 1), e.y);
    }
}

// One wave per output row, lane = dim. fp16 gathers (2 B/lane), fp32 accum,
// 8-deep batched loads into 4 rotating accumulators.
__global__ __launch_bounds__(256) void spmm_h_kernel(
        const int* __restrict__ rp, const int2* __restrict__ sce,
        const __half* __restrict__ xin, __half* __restrict__ xnxt,
        int n_nodes) {
    int wid = (int)(((long long)blockIdx.x * blockDim.x + threadIdx.x) >> 6);
    int lane = threadIdx.x & 63;
    if (wid >= n_nodes) return;
    int beg = __builtin_amdgcn_readfirstlane(rp[wid]);
    int end = __builtin_amdgcn_readfirstlane(rp[wid + 1]);
    const unsigned long long* __restrict__ sceq = (const unsigned long long*)sce;
    float s0 = 0.f, s1 = 0.f, s2 = 0.f, s3 = 0.f;
    int p = beg;
    for (; p + 8 <= end; p += 8) {
        unsigned long long u0 = __builtin_nontemporal_load(sceq + p + 0);
        unsigned long long u1 = __builtin_nontemporal_load(sceq + p + 1);
        unsigned long long u2 = __builtin_nontemporal_load(sceq + p + 2);
        unsigned long long u3 = __builtin_nontemporal_load(sceq + p + 3);
        unsigned long long u4 = __builtin_nontemporal_load(sceq + p + 4);
        unsigned long long u5 = __builtin_nontemporal_load(sceq + p + 5);
        unsigned long long u6 = __builtin_nontemporal_load(sceq + p + 6);
        unsigned long long u7 = __builtin_nontemporal_load(sceq + p + 7);
        float g0 = __half2float(xin[((int)(unsigned)u0) * EMB_C + lane]);
        float g1 = __half2float(xin[((int)(unsigned)u1) * EMB_C + lane]);
        float g2 = __half2float(xin[((int)(unsigned)u2) * EMB_C + lane]);
        float g3 = __half2float(xin[((int)(unsigned)u3) * EMB_C + lane]);
        float g4 = __half2float(xin[((int)(unsigned)u4) * EMB_C + lane]);
        float g5 = __half2float(xin[((int)(unsigned)u5) * EMB_C + lane]);
        float g6 = __half2float(xin[((int)(unsigned)u6) * EMB_C + lane]);
        float g7 = __half2float(xin[((int)(unsigned)u7) * EMB_C + lane]);
        s0 = fmaf(__int_as_float((int)(u0 >> 32)), g0, s0);
        s1 = fmaf(__int_as_float((int)(u1 >> 32)), g1, s1);
        s2 = fmaf(__int_as_float((int)(u2 >> 32)), g2, s2);
        s3 = fmaf(__int_as_float((int)(u3 >> 32)), g3, s3);
        s0 = fmaf(__int_as_float((int)(u4 >> 32)), g4, s0);
        s1 = fmaf(__int_as_float((int)(u5 >> 32)), g5, s1);
        s2 = fmaf(__int_as_float((int)(u6 >> 32)), g6, s2);
        s3 = fmaf(__int_as_float((int)(u7 >> 32)), g7, s3);
    }
    for (; p + 4 <= end; p += 4) {
        unsigned long long u0 = __builtin_nontemporal_load(sceq + p + 0);
        unsigned long long u1 = __builtin_nontemporal_load(sceq + p + 1);
        unsigned long long u2 = __builtin_nontemporal_load(sceq + p + 2);
        unsigned long long u3 = __builtin_nontemporal_load(sceq + p + 3);
        float g0 = __half2float(xin[((int)(unsigned)u0) * EMB_C + lane]);
        float g1 = __half2float(xin[((int)(unsigned)u1) * EMB_C + lane]);
        float g2 = __half2float(xin[((int)(unsigned)u2) * EMB_C + lane]);
        float g3 = __half2float(xin[((int)(unsigned)u3) * EMB_C + lane]);
        s0 = fmaf(__int_as_float((int)(u0 >> 32)), g0, s0);
        s1 = fmaf(__int_as_float((int)(u1 >> 32)), g1, s1);
        s2 = fmaf(__int_as_float((int)(u2 >> 32)), g2, s2);
        s3 = fmaf(__int_as_float((int)(u3 >> 32)), g3, s3);
    }
    for (; p < end; ++p) {
        unsigned long long u = __builtin_nontemporal_load(sceq + p);
        s0 = fmaf(__int_as_float((int)(u >> 32)),
                  __half2float(xin[((int)(unsigned)u) * EMB_C + lane]), s0);
    }
    float s = (s0 + s1) + (s2 + s3);
    unsigned short hs = __half_as_ushort(__float2half(s));
    __builtin_nontemporal_store(hs, (unsigned short*)(xnxt + wid * EMB_C + lane));
}

// out = 0.25 * (x0+x1+x2+x3)[row] at gathered rows (fp16 -> fp32 sum).
__global__ __launch_bounds__(256) void gather_h_kernel(
        const __half* __restrict__ p0, const __half* __restrict__ p1,
        const __half* __restrict__ p2, const __half* __restrict__ p3,
        const int* __restrict__ users, const int* __restrict__ pos,
        const int* __restrict__ neg, float* __restrict__ out,
        int batch, float scale) {
    long long gid = (long long)blockIdx.x * blockDim.x + threadIdx.x;
    long long per = (long long)batch * EMB_C;
    if (gid >= 3 * per) return;
    int which = (int)(gid / per);
    long long rem = gid - (long long)which * per;
    int b = (int)(rem >> 6);
    int d = (int)(rem & 63);
    long long row;
    if (which == 0)      row = users[b];
    else if (which == 1) row = (long long)N_USER_C + pos[b];
    else                 row = (long long)N_USER_C + neg[b];
    long long idx = row * EMB_C + d;
    out[gid] = scale * (__half2float(p0[idx]) + __half2float(p1[idx]) +
                        __half2float(p2[idx]) + __half2float(p3[idx]));
}

// ======================= fallback (atomic) kernels ========================

__global__ __launch_bounds__(256) void fill_kernel(
        const float4* __restrict__ ue, const float4* __restrict__ ie,
        float4* __restrict__ x0, float4* __restrict__ a,
        float4* __restrict__ b, long long u4, long long t4) {
    long long i = (long long)blockIdx.x * blockDim.x + threadIdx.x;
    if (i >= t4) return;
    float4 v = (i < u4) ? ue[i] : ie[i - u4];
    x0[i] = v;
    a[i] = v;
    b[i] = make_float4(0.f, 0.f, 0.f, 0.f);
}

__global__ __launch_bounds__(256) void spmm_kernel(
        const float* __restrict__ vals, const int* __restrict__ rows,
        const int* __restrict__ cols, const float* __restrict__ xin,
        float* __restrict__ xout, int nnz) {
    long long gid = (long long)blockIdx.x * blockDim.x + threadIdx.x;
    int e = (int)(gid >> 6);
    int d = (int)(gid & 63);
    if (e >= nnz) return;
    unsafeAtomicAdd(&xout[(long long)rows[e] * EMB_C + d],
                    vals[e] * xin[(long long)cols[e] * EMB_C + d]);
}

__global__ __launch_bounds__(256) void acczero_kernel(
        float4* __restrict__ acc, const float4* __restrict__ src,
        float4* __restrict__ tozero, long long n4) {
    long long i = (long long)blockIdx.x * blockDim.x + threadIdx.x;
    if (i >= n4) return;
    float4 a = acc[i], s = src[i];
    a.x += s.x; a.y += s.y; a.z += s.z; a.w += s.w;
    acc[i] = a;
    if (tozero) tozero[i] = make_float4(0.f, 0.f, 0.f, 0.f);
}

__global__ __launch_bounds__(256) void gather_f_kernel(
        const float* __restrict__ acc,
        const int* __restrict__ users, const int* __restrict__ pos,
        const int* __restrict__ neg, float* __restrict__ out,
        int batch, float scale) {
    long long gid = (long long)blockIdx.x * blockDim.x + threadIdx.x;
    long long per = (long long)batch * EMB_C;
    if (gid >= 3 * per) return;
    int which = (int)(gid / per);
    long long rem = gid - (long long)which * per;
    int b = (int)(rem >> 6);
    int d = (int)(rem & 63);
    long long row;
    if (which == 0)      row = users[b];
    else if (which == 1) row = (long long)N_USER_C + pos[b];
    else                 row = (long long)N_USER_C + neg[b];
    out[gid] = scale * acc[row * EMB_C + d];
}

// ================================ driver ==================================

extern "C" void kernel_launch(void* const* d_in, const int* in_sizes, int n_in,
                              void* d_out, int out_size, void* d_ws, size_t ws_size,
                              hipStream_t stream) {
    const float* ue    = (const float*)d_in[0];
    const float* ie    = (const float*)d_in[1];
    const float* vals  = (const float*)d_in[2];
    const int*   rows  = (const int*)d_in[3];
    const int*   cols  = (const int*)d_in[4];
    const int*   users = (const int*)d_in[5];
    const int*   pos   = (const int*)d_in[6];
    const int*   neg   = (const int*)d_in[7];
    float* out = (float*)d_out;

    const int nnz   = in_sizes[2];
    const int batch = in_sizes[5];
    const long long uelems = (long long)in_sizes[0];
    const long long total  = uelems + (long long)in_sizes[1];  // n_nodes * EMB
    const int n_nodes = (int)(total / EMB_C);
    const long long u4 = uelems / 4, t4 = total / 4;

    const int T = 256;
    const int fill_blocks = (int)((t4 + T - 1) / T);
    const int gath_blocks = (int)((3LL * batch * EMB_C + T - 1) / T);
    const int spmm_blocks = (int)(((long long)n_nodes * EMB_C + T - 1) / T);
    const int nb = (n_nodes + BROWS - 1) / BROWS;
    const int chunk_blocks = (nnz + CHUNK - 1) / CHUNK;

    // fp16 layout (bytes): x0..x3 (total*2 each) | rp(RN*4) | bhist/bbase/gcur
    // (1024*4 each) | sce (nnz*8) | bin (nnz*8)
    const long long RN = ((n_nodes + 1 + 15) / 16) * 16;
    const size_t xbytes = (size_t)total * 2;
    const size_t needH = 4 * xbytes + (size_t)(RN + 3072) * 4 + (size_t)nnz * 16;
    const bool fits = (nb <= NBMAX) && (n_nodes <= (1 << COLBITS));

    char* wb = (char*)d_ws;

    if (fits && ws_size >= needH) {
        __half* x0 = (__half*)wb;
        __half* x1 = (__half*)(wb + xbytes);
        __half* x2 = (__half*)(wb + 2 * xbytes);
        __half* x3 = (__half*)(wb + 3 * xbytes);
        int*   rp    = (int*)(wb + 4 * xbytes);
        int*   bhist = rp + RN;
        int*   bbase = bhist + 1024;
        int*   gcur  = bbase + 1024;
        int2*  sce   = (int2*)(gcur + 1024);
        int2*  bin   = sce + nnz;

        fill_h_kernel<<<fill_blocks, T, 0, stream>>>(
            (const float4*)ue, (const float4*)ie,
            (ushort4*)x0, (int4*)bhist, u4, t4, 1024 / 4);

        buckethist_kernel<<<chunk_blocks, T, 0, stream>>>(rows, bhist, nnz, nb);
        bucketscan_kernel<<<1, 1024, 0, stream>>>(bhist, bbase, gcur, rp, nb, nnz, n_nodes);
        binscatter_kernel<<<chunk_blocks, T, 0, stream>>>(rows, cols, vals, gcur, bin, nnz, nb);
        finscatter_kernel<<<nb, 512, 0, stream>>>(bin, bbase, rp, sce, n_nodes);

        spmm_h_kernel<<<spmm_blocks, T, 0, stream>>>(rp, sce, x0, x1, n_nodes);
        spmm_h_kernel<<<spmm_blocks, T, 0, stream>>>(rp, sce, x1, x2, n_nodes);
        spmm_h_kernel<<<spmm_blocks, T, 0, stream>>>(rp, sce, x2, x3, n_nodes);

        gather_h_kernel<<<gath_blocks, T, 0, stream>>>(
            x0, x1, x2, x3, users, pos, neg, out, batch, 0.25f);
    } else {
        // ---- Tier C: 3-buffer fp32 atomic fallback ----
        float* cur = (float*)wb;
        float* nxt = cur + total;
        float* acc = nxt + total;
        fill_kernel<<<fill_blocks, T, 0, stream>>>(
            (const float4*)ue, (const float4*)ie,
            (float4*)cur, (float4*)acc, (float4*)nxt, u4, t4);
        const int espmm_blocks = (int)(((long long)nnz * EMB_C + T - 1) / T);
        for (int l = 0; l < 3; ++l) {
            spmm_kernel<<<espmm_blocks, T, 0, stream>>>(vals, rows, cols, cur, nxt, nnz);
            float4* tz = (l < 2) ? (float4*)cur : nullptr;
            acczero_kernel<<<fill_blocks, T, 0, stream>>>(
                (float4*)acc, (const float4*)nxt, tz, t4);
            float* t = cur; cur = nxt; nxt = t;
        }
        gather_f_kernel<<<gath_blocks, T, 0, stream>>>(
            acc, users, pos, neg, out, batch, 0.0625f);
    }
}

// Round 12
// 444.388 us; speedup vs baseline: 1.0967x; 1.0967x over previous
//
#include <hip/hip_runtime.h>
#include <hip/hip_fp16.h>

#define EMB_C 64
#define N_USER_C 100000
#define BROWS 256        // rows per bucket
#define BSHIFT 8
#define COLBITS 18       // col fits 18 bits (n_nodes <= 262144)
#define CHUNK 8192       // edges per binning workgroup
#define NBMAX 640        // max buckets supported (padded hist row)

// ============================ CSR path kernels ============================

// x0h = fp16(concat(user_emb, item_emb)).
__global__ __launch_bounds__(256) void fill_h_kernel(
        const float4* __restrict__ ue, const float4* __restrict__ ie,
        ushort4* __restrict__ x0, long long u4, long long t4) {
    long long i = (long long)blockIdx.x * blockDim.x + threadIdx.x;
    if (i >= t4) return;
    float4 v = (i < u4) ? ue[i] : ie[i - u4];
    ushort4 h;
    h.x = __half_as_ushort(__float2half(v.x));
    h.y = __half_as_ushort(__float2half(v.y));
    h.z = __half_as_ushort(__float2half(v.z));
    h.w = __half_as_ushort(__float2half(v.w));
    x0[i] = h;
}

// Per-chunk bucket histogram -> ghist[chunk][b] (coalesced, no global atomics).
__global__ __launch_bounds__(256) void chunkhist_kernel(
        const int* __restrict__ rows, int* __restrict__ ghist, int nnz, int nb) {
    __shared__ int hist[NBMAX];
    for (int b = threadIdx.x; b < nb; b += 256) hist[b] = 0;
    __syncthreads();
    const int c0 = blockIdx.x * CHUNK;
    for (int i = threadIdx.x; i < CHUNK; i += 256) {
        int e = c0 + i;
        if (e < nnz) atomicAdd(&hist[rows[e] >> BSHIFT], 1);
    }
    __syncthreads();
    for (int b = threadIdx.x; b < nb; b += 256)
        ghist[blockIdx.x * NBMAX + b] = hist[b];
}

// One WG per bucket: exclusive prefix over chunks written back into ghist;
// bucket total -> btot[b].
__global__ __launch_bounds__(256) void colscan_kernel(
        int* __restrict__ ghist, int* __restrict__ btot, int NC, int nb) {
    __shared__ int sh[256];
    const int b = blockIdx.x;
    int run = 0;
    for (int c0 = 0; c0 < NC; c0 += 256) {
        int c = c0 + threadIdx.x;
        int v = (c < NC) ? ghist[c * NBMAX + b] : 0;
        sh[threadIdx.x] = v;
        __syncthreads();
        for (int off = 1; off < 256; off <<= 1) {
            int t = (threadIdx.x >= off) ? sh[threadIdx.x - off] : 0;
            __syncthreads();
            sh[threadIdx.x] += t;
            __syncthreads();
        }
        if (c < NC) ghist[c * NBMAX + b] = run + sh[threadIdx.x] - v;
        run += sh[255];
        __syncthreads();
    }
    if (threadIdx.x == 0) btot[b] = run;
}

// Single block: exclusive-scan btot -> bbase; bbase[nb]=nnz; rp[n_nodes]=nnz.
__global__ __launch_bounds__(1024) void bucketscan_kernel(
        const int* __restrict__ btot, int* __restrict__ bbase,
        int* __restrict__ rp, int nb, int nnz, int n_nodes) {
    __shared__ int sh[1024];
    int v = (threadIdx.x < nb) ? btot[threadIdx.x] : 0;
    sh[threadIdx.x] = v;
    __syncthreads();
    for (int off = 1; off < 1024; off <<= 1) {
        int t = (threadIdx.x >= off) ? sh[threadIdx.x - off] : 0;
        __syncthreads();
        sh[threadIdx.x] += t;
        __syncthreads();
    }
    if (threadIdx.x < nb) bbase[threadIdx.x] = sh[threadIdx.x] - v;
    if (threadIdx.x == 0) { bbase[nb] = nnz; rp[n_nodes] = nnz; }
}

// Single pass: LDS cursors = bbase + chunk prefix; one LDS atomic per edge,
// ZERO global atomics. Payload {(row_low<<COLBITS)|col, val_bits}.
__global__ __launch_bounds__(256) void binscatter2_kernel(
        const int* __restrict__ rows, const int* __restrict__ cols,
        const float* __restrict__ vals, const int* __restrict__ ghist,
        const int* __restrict__ bbase, int2* __restrict__ bin, int nnz, int nb) {
    __shared__ int cur[NBMAX];
    const int chunk = blockIdx.x;
    const int c0 = chunk * CHUNK;
    for (int b = threadIdx.x; b < nb; b += 256)
        cur[b] = bbase[b] + ghist[chunk * NBMAX + b];
    __syncthreads();
    for (int i = threadIdx.x; i < CHUNK; i += 256) {
        int e = c0 + i;
        if (e >= nnz) break;
        int r = rows[e];
        int b = r >> BSHIFT;
        int k = atomicAdd(&cur[b], 1);
        bin[k] = make_int2(((r & (BROWS - 1)) << COLBITS) | cols[e],
                           __float_as_int(vals[e]));
    }
}

// Phase 2 (one WG of 512 per bucket): count rows in LDS, scan (256 lanes),
// WRITE rp for this bucket, then scatter edges into row order.
__global__ __launch_bounds__(512) void finscatter_kernel(
        const int2* __restrict__ bin, const int* __restrict__ bbase,
        int* __restrict__ rp, int2* __restrict__ sce, int n_nodes) {
    __shared__ int cnt[BROWS];
    __shared__ int sh[BROWS];
    __shared__ int cur[BROWS];
    const int row0 = blockIdx.x << BSHIFT;
    const int tid = threadIdx.x;
    if (tid < BROWS) cnt[tid] = 0;
    __syncthreads();
    const int bb = bbase[blockIdx.x];
    const int be = bbase[blockIdx.x + 1];
    for (int p = bb + tid; p < be; p += 512)
        atomicAdd(&cnt[bin[p].x >> COLBITS], 1);
    __syncthreads();
    int v = 0;
    if (tid < BROWS) { v = cnt[tid]; sh[tid] = v; }
    __syncthreads();
    for (int off = 1; off < BROWS; off <<= 1) {
        int t = (tid < BROWS && tid >= off) ? sh[tid - off] : 0;
        __syncthreads();
        if (tid < BROWS) sh[tid] += t;
        __syncthreads();
    }
    if (tid < BROWS) {
        int excl = sh[tid] - v;
        cur[tid] = excl;
        if (row0 + tid < n_nodes) rp[row0 + tid] = bb + excl;   // coalesced rp
    }
    __syncthreads();
    for (int p = bb + tid; p < be; p += 512) {
        int2 e = bin[p];
        int rl = e.x >> COLBITS;
        int k = atomicAdd(&cur[rl], 1);
        sce[bb + k] = make_int2(e.x & ((1 << COLBITS) - 1), e.y);
    }
}

// One wave per output row, lane = dim. fp16 gathers (2 B/lane), fp32 accum,
// 8-deep batched loads into 4 rotating accumulators.
__global__ __launch_bounds__(256) void spmm_h_kernel(
        const int* __restrict__ rp, const int2* __restrict__ sce,
        const __half* __restrict__ xin, __half* __restrict__ xnxt,
        int n_nodes) {
    int wid = (int)(((long long)blockIdx.x * blockDim.x + threadIdx.x) >> 6);
    int lane = threadIdx.x & 63;
    if (wid >= n_nodes) return;
    int beg = __builtin_amdgcn_readfirstlane(rp[wid]);
    int end = __builtin_amdgcn_readfirstlane(rp[wid + 1]);
    const unsigned long long* __restrict__ sceq = (const unsigned long long*)sce;
    float s0 = 0.f, s1 = 0.f, s2 = 0.f, s3 = 0.f;
    int p = beg;
    for (; p + 8 <= end; p += 8) {
        unsigned long long u0 = __builtin_nontemporal_load(sceq + p + 0);
        unsigned long long u1 = __builtin_nontemporal_load(sceq + p + 1);
        unsigned long long u2 = __builtin_nontemporal_load(sceq + p + 2);
        unsigned long long u3 = __builtin_nontemporal_load(sceq + p + 3);
        unsigned long long u4 = __builtin_nontemporal_load(sceq + p + 4);
        unsigned long long u5 = __builtin_nontemporal_load(sceq + p + 5);
        unsigned long long u6 = __builtin_nontemporal_load(sceq + p + 6);
        unsigned long long u7 = __builtin_nontemporal_load(sceq + p + 7);
        float g0 = __half2float(xin[((int)(unsigned)u0) * EMB_C + lane]);
        float g1 = __half2float(xin[((int)(unsigned)u1) * EMB_C + lane]);
        float g2 = __half2float(xin[((int)(unsigned)u2) * EMB_C + lane]);
        float g3 = __half2float(xin[((int)(unsigned)u3) * EMB_C + lane]);
        float g4 = __half2float(xin[((int)(unsigned)u4) * EMB_C + lane]);
        float g5 = __half2float(xin[((int)(unsigned)u5) * EMB_C + lane]);
        float g6 = __half2float(xin[((int)(unsigned)u6) * EMB_C + lane]);
        float g7 = __half2float(xin[((int)(unsigned)u7) * EMB_C + lane]);
        s0 = fmaf(__int_as_float((int)(u0 >> 32)), g0, s0);
        s1 = fmaf(__int_as_float((int)(u1 >> 32)), g1, s1);
        s2 = fmaf(__int_as_float((int)(u2 >> 32)), g2, s2);
        s3 = fmaf(__int_as_float((int)(u3 >> 32)), g3, s3);
        s0 = fmaf(__int_as_float((int)(u4 >> 32)), g4, s0);
        s1 = fmaf(__int_as_float((int)(u5 >> 32)), g5, s1);
        s2 = fmaf(__int_as_float((int)(u6 >> 32)), g6, s2);
        s3 = fmaf(__int_as_float((int)(u7 >> 32)), g7, s3);
    }
    for (; p + 4 <= end; p += 4) {
        unsigned long long u0 = __builtin_nontemporal_load(sceq + p + 0);
        unsigned long long u1 = __builtin_nontemporal_load(sceq + p + 1);
        unsigned long long u2 = __builtin_nontemporal_load(sceq + p + 2);
        unsigned long long u3 = __builtin_nontemporal_load(sceq + p + 3);
        float g0 = __half2float(xin[((int)(unsigned)u0) * EMB_C + lane]);
        float g1 = __half2float(xin[((int)(unsigned)u1) * EMB_C + lane]);
        float g2 = __half2float(xin[((int)(unsigned)u2) * EMB_C + lane]);
        float g3 = __half2float(xin[((int)(unsigned)u3) * EMB_C + lane]);
        s0 = fmaf(__int_as_float((int)(u0 >> 32)), g0, s0);
        s1 = fmaf(__int_as_float((int)(u1 >> 32)), g1, s1);
        s2 = fmaf(__int_as_float((int)(u2 >> 32)), g2, s2);
        s3 = fmaf(__int_as_float((int)(u3 >> 32)), g3, s3);
    }
    for (; p < end; ++p) {
        unsigned long long u = __builtin_nontemporal_load(sceq + p);
        s0 = fmaf(__int_as_float((int)(u >> 32)),
                  __half2float(xin[((int)(unsigned)u) * EMB_C + lane]), s0);
    }
    float s = (s0 + s1) + (s2 + s3);
    unsigned short hs = __half_as_ushort(__float2half(s));
    __builtin_nontemporal_store(hs, (unsigned short*)(xnxt + wid * EMB_C + lane));
}

// out = 0.25 * (x0+x1+x2+x3)[row] at gathered rows (fp16 -> fp32 sum).
__global__ __launch_bounds__(256) void gather_h_kernel(
        const __half* __restrict__ p0, const __half* __restrict__ p1,
        const __half* __restrict__ p2, const __half* __restrict__ p3,
        const int* __restrict__ users, const int* __restrict__ pos,
        const int* __restrict__ neg, float* __restrict__ out,
        int batch, float scale) {
    long long gid = (long long)blockIdx.x * blockDim.x + threadIdx.x;
    long long per = (long long)batch * EMB_C;
    if (gid >= 3 * per) return;
    int which = (int)(gid / per);
    long long rem = gid - (long long)which * per;
    int b = (int)(rem >> 6);
    int d = (int)(rem & 63);
    long long row;
    if (which == 0)      row = users[b];
    else if (which == 1) row = (long long)N_USER_C + pos[b];
    else                 row = (long long)N_USER_C + neg[b];
    long long idx = row * EMB_C + d;
    out[gid] = scale * (__half2float(p0[idx]) + __half2float(p1[idx]) +
                        __half2float(p2[idx]) + __half2float(p3[idx]));
}

// ======================= fallback (atomic) kernels ========================

__global__ __launch_bounds__(256) void fill_kernel(
        const float4* __restrict__ ue, const float4* __restrict__ ie,
        float4* __restrict__ x0, float4* __restrict__ a,
        float4* __restrict__ b, long long u4, long long t4) {
    long long i = (long long)blockIdx.x * blockDim.x + threadIdx.x;
    if (i >= t4) return;
    float4 v = (i < u4) ? ue[i] : ie[i - u4];
    x0[i] = v;
    a[i] = v;
    b[i] = make_float4(0.f, 0.f, 0.f, 0.f);
}

__global__ __launch_bounds__(256) void spmm_kernel(
        const float* __restrict__ vals, const int* __restrict__ rows,
        const int* __restrict__ cols, const float* __restrict__ xin,
        float* __restrict__ xout, int nnz) {
    long long gid = (long long)blockIdx.x * blockDim.x + threadIdx.x;
    int e = (int)(gid >> 6);
    int d = (int)(gid & 63);
    if (e >= nnz) return;
    unsafeAtomicAdd(&xout[(long long)rows[e] * EMB_C + d],
                    vals[e] * xin[(long long)cols[e] * EMB_C + d]);
}

__global__ __launch_bounds__(256) void acczero_kernel(
        float4* __restrict__ acc, const float4* __restrict__ src,
        float4* __restrict__ tozero, long long n4) {
    long long i = (long long)blockIdx.x * blockDim.x + threadIdx.x;
    if (i >= n4) return;
    float4 a = acc[i], s = src[i];
    a.x += s.x; a.y += s.y; a.z += s.z; a.w += s.w;
    acc[i] = a;
    if (tozero) tozero[i] = make_float4(0.f, 0.f, 0.f, 0.f);
}

__global__ __launch_bounds__(256) void gather_f_kernel(
        const float* __restrict__ acc,
        const int* __restrict__ users, const int* __restrict__ pos,
        const int* __restrict__ neg, float* __restrict__ out,
        int batch, float scale) {
    long long gid = (long long)blockIdx.x * blockDim.x + threadIdx.x;
    long long per = (long long)batch * EMB_C;
    if (gid >= 3 * per) return;
    int which = (int)(gid / per);
    long long rem = gid - (long long)which * per;
    int b = (int)(rem >> 6);
    int d = (int)(rem & 63);
    long long row;
    if (which == 0)      row = users[b];
    else if (which == 1) row = (long long)N_USER_C + pos[b];
    else                 row = (long long)N_USER_C + neg[b];
    out[gid] = scale * acc[row * EMB_C + d];
}

// ================================ driver ==================================

extern "C" void kernel_launch(void* const* d_in, const int* in_sizes, int n_in,
                              void* d_out, int out_size, void* d_ws, size_t ws_size,
                              hipStream_t stream) {
    const float* ue    = (const float*)d_in[0];
    const float* ie    = (const float*)d_in[1];
    const float* vals  = (const float*)d_in[2];
    const int*   rows  = (const int*)d_in[3];
    const int*   cols  = (const int*)d_in[4];
    const int*   users = (const int*)d_in[5];
    const int*   pos   = (const int*)d_in[6];
    const int*   neg   = (const int*)d_in[7];
    float* out = (float*)d_out;

    const int nnz   = in_sizes[2];
    const int batch = in_sizes[5];
    const long long uelems = (long long)in_sizes[0];
    const long long total  = uelems + (long long)in_sizes[1];  // n_nodes * EMB
    const int n_nodes = (int)(total / EMB_C);
    const long long u4 = uelems / 4, t4 = total / 4;

    const int T = 256;
    const int fill_blocks = (int)((t4 + T - 1) / T);
    const int gath_blocks = (int)((3LL * batch * EMB_C + T - 1) / T);
    const int spmm_blocks = (int)(((long long)n_nodes * EMB_C + T - 1) / T);
    const int nb = (n_nodes + BROWS - 1) / BROWS;
    const int NC = (nnz + CHUNK - 1) / CHUNK;

    // fp16 layout (bytes): x0..x3 | rp(RN*4) | btot(1024*4) | bbase(1024*4) |
    // ghist(NC*NBMAX*4) | sce(nnz*8) | bin(nnz*8)
    const long long RN = ((n_nodes + 1 + 15) / 16) * 16;
    const size_t xbytes = (size_t)total * 2;
    const size_t ghist_bytes = (size_t)NC * NBMAX * 4;
    const size_t needH = 4 * xbytes + (size_t)(RN + 2048) * 4 + ghist_bytes
                       + (size_t)nnz * 16;
    const bool fits = (nb <= NBMAX) && (n_nodes <= (1 << COLBITS));

    char* wb = (char*)d_ws;

    if (fits && ws_size >= needH) {
        __half* x0 = (__half*)wb;
        __half* x1 = (__half*)(wb + xbytes);
        __half* x2 = (__half*)(wb + 2 * xbytes);
        __half* x3 = (__half*)(wb + 3 * xbytes);
        int*   rp    = (int*)(wb + 4 * xbytes);
        int*   btot  = rp + RN;
        int*   bbase = btot + 1024;
        int*   ghist = bbase + 1024;
        int2*  sce   = (int2*)(ghist + (size_t)NC * NBMAX);
        int2*  bin   = sce + nnz;

        fill_h_kernel<<<fill_blocks, T, 0, stream>>>(
            (const float4*)ue, (const float4*)ie, (ushort4*)x0, u4, t4);

        chunkhist_kernel<<<NC, T, 0, stream>>>(rows, ghist, nnz, nb);
        colscan_kernel<<<nb, T, 0, stream>>>(ghist, btot, NC, nb);
        bucketscan_kernel<<<1, 1024, 0, stream>>>(btot, bbase, rp, nb, nnz, n_nodes);
        binscatter2_kernel<<<NC, T, 0, stream>>>(rows, cols, vals, ghist, bbase,
                                                 bin, nnz, nb);
        finscatter_kernel<<<nb, 512, 0, stream>>>(bin, bbase, rp, sce, n_nodes);

        spmm_h_kernel<<<spmm_blocks, T, 0, stream>>>(rp, sce, x0, x1, n_nodes);
        spmm_h_kernel<<<spmm_blocks, T, 0, stream>>>(rp, sce, x1, x2, n_nodes);
        spmm_h_kernel<<<spmm_blocks, T, 0, stream>>>(rp, sce, x2, x3, n_nodes);

        gather_h_kernel<<<gath_blocks, T, 0, stream>>>(
            x0, x1, x2, x3, users, pos, neg, out, batch, 0.25f);
    } else {
        // ---- Tier C: 3-buffer fp32 atomic fallback ----
        float* cur = (float*)wb;
        float* nxt = cur + total;
        float* acc = nxt + total;
        fill_kernel<<<fill_blocks, T, 0, stream>>>(
            (const float4*)ue, (const float4*)ie,
            (float4*)cur, (float4*)acc, (float4*)nxt, u4, t4);
        const int espmm_blocks = (int)(((long long)nnz * EMB_C + T - 1) / T);
        for (int l = 0; l < 3; ++l) {
            spmm_kernel<<<espmm_blocks, T, 0, stream>>>(vals, rows, cols, cur, nxt, nnz);
            float4* tz = (l < 2) ? (float4*)cur : nullptr;
            acczero_kernel<<<fill_blocks, T, 0, stream>>>(
                (float4*)acc, (const float4*)nxt, tz, t4);
            float* t = cur; cur = nxt; nxt = t;
        }
        gather_f_kernel<<<gath_blocks, T, 0, stream>>>(
            acc, users, pos, neg, out, batch, 0.0625f);
    }
}

// Round 13
// 441.865 us; speedup vs baseline: 1.1029x; 1.0057x over previous
//
#include <hip/hip_runtime.h>
#include <hip/hip_fp16.h>

#define EMB_C 64
#define N_USER_C 100000
#define BROWS 256        // rows per bucket
#define BSHIFT 8
#define COLBITS 18       // col fits 18 bits (n_nodes <= 262144)
#define NBMAX 640        // max buckets supported (padded hist row)

// ============================ CSR path kernels ============================

// x0h = fp16(concat(user_emb, item_emb)).
__global__ __launch_bounds__(256) void fill_h_kernel(
        const float4* __restrict__ ue, const float4* __restrict__ ie,
        ushort4* __restrict__ x0, long long u4, long long t4) {
    long long i = (long long)blockIdx.x * blockDim.x + threadIdx.x;
    if (i >= t4) return;
    float4 v = (i < u4) ? ue[i] : ie[i - u4];
    ushort4 h;
    h.x = __half_as_ushort(__float2half(v.x));
    h.y = __half_as_ushort(__float2half(v.y));
    h.z = __half_as_ushort(__float2half(v.z));
    h.w = __half_as_ushort(__float2half(v.w));
    x0[i] = h;
}

// Per-chunk bucket histogram -> ghist[chunk][b] (coalesced, no global atomics).
__global__ __launch_bounds__(256) void chunkhist_kernel(
        const int* __restrict__ rows, int* __restrict__ ghist, int nnz, int nb,
        int csz) {
    __shared__ int hist[NBMAX];
    for (int b = threadIdx.x; b < nb; b += 256) hist[b] = 0;
    __syncthreads();
    const long long c0 = (long long)blockIdx.x * csz;
    for (int i = threadIdx.x; i < csz; i += 256) {
        long long e = c0 + i;
        if (e < nnz) atomicAdd(&hist[rows[e] >> BSHIFT], 1);
    }
    __syncthreads();
    for (int b = threadIdx.x; b < nb; b += 256)
        ghist[blockIdx.x * NBMAX + b] = hist[b];
}

// One WG per bucket: exclusive prefix over chunks written back into ghist;
// bucket total -> btot[b].
__global__ __launch_bounds__(256) void colscan_kernel(
        int* __restrict__ ghist, int* __restrict__ btot, int NC, int nb) {
    __shared__ int sh[256];
    const int b = blockIdx.x;
    int run = 0;
    for (int c0 = 0; c0 < NC; c0 += 256) {
        int c = c0 + threadIdx.x;
        int v = (c < NC) ? ghist[c * NBMAX + b] : 0;
        sh[threadIdx.x] = v;
        __syncthreads();
        for (int off = 1; off < 256; off <<= 1) {
            int t = (threadIdx.x >= off) ? sh[threadIdx.x - off] : 0;
            __syncthreads();
            sh[threadIdx.x] += t;
            __syncthreads();
        }
        if (c < NC) ghist[c * NBMAX + b] = run + sh[threadIdx.x] - v;
        run += sh[255];
        __syncthreads();
    }
    if (threadIdx.x == 0) btot[b] = run;
}

// Single block: exclusive-scan btot -> bbase; bbase[nb]=nnz; rp[n_nodes]=nnz.
__global__ __launch_bounds__(1024) void bucketscan_kernel(
        const int* __restrict__ btot, int* __restrict__ bbase,
        int* __restrict__ rp, int nb, int nnz, int n_nodes) {
    __shared__ int sh[1024];
    int v = (threadIdx.x < nb) ? btot[threadIdx.x] : 0;
    sh[threadIdx.x] = v;
    __syncthreads();
    for (int off = 1; off < 1024; off <<= 1) {
        int t = (threadIdx.x >= off) ? sh[threadIdx.x - off] : 0;
        __syncthreads();
        sh[threadIdx.x] += t;
        __syncthreads();
    }
    if (threadIdx.x < nb) bbase[threadIdx.x] = sh[threadIdx.x] - v;
    if (threadIdx.x == 0) { bbase[nb] = nnz; rp[n_nodes] = nnz; }
}

// Single pass: LDS cursors = bbase + chunk prefix; one LDS atomic per edge,
// ZERO global atomics. Payload {(row_low<<COLBITS)|col, val_bits}.
__global__ __launch_bounds__(256) void binscatter2_kernel(
        const int* __restrict__ rows, const int* __restrict__ cols,
        const float* __restrict__ vals, const int* __restrict__ ghist,
        const int* __restrict__ bbase, int2* __restrict__ bin, int nnz, int nb,
        int csz) {
    __shared__ int cur[NBMAX];
    const int chunk = blockIdx.x;
    const long long c0 = (long long)chunk * csz;
    for (int b = threadIdx.x; b < nb; b += 256)
        cur[b] = bbase[b] + ghist[chunk * NBMAX + b];
    __syncthreads();
    for (int i = threadIdx.x; i < csz; i += 256) {
        long long e = c0 + i;
        if (e >= nnz) break;
        int r = rows[e];
        int b = r >> BSHIFT;
        int k = atomicAdd(&cur[b], 1);
        bin[k] = make_int2(((r & (BROWS - 1)) << COLBITS) | cols[e],
                           __float_as_int(vals[e]));
    }
}

// Phase 2 (one WG of 512 per bucket): count rows in LDS, scan (256 lanes),
// WRITE rp for this bucket, then scatter edges into row order.
__global__ __launch_bounds__(512) void finscatter_kernel(
        const int2* __restrict__ bin, const int* __restrict__ bbase,
        int* __restrict__ rp, int2* __restrict__ sce, int n_nodes) {
    __shared__ int cnt[BROWS];
    __shared__ int sh[BROWS];
    __shared__ int cur[BROWS];
    const int row0 = blockIdx.x << BSHIFT;
    const int tid = threadIdx.x;
    if (tid < BROWS) cnt[tid] = 0;
    __syncthreads();
    const int bb = bbase[blockIdx.x];
    const int be = bbase[blockIdx.x + 1];
    for (int p = bb + tid; p < be; p += 512)
        atomicAdd(&cnt[bin[p].x >> COLBITS], 1);
    __syncthreads();
    int v = 0;
    if (tid < BROWS) { v = cnt[tid]; sh[tid] = v; }
    __syncthreads();
    for (int off = 1; off < BROWS; off <<= 1) {
        int t = (tid < BROWS && tid >= off) ? sh[tid - off] : 0;
        __syncthreads();
        if (tid < BROWS) sh[tid] += t;
        __syncthreads();
    }
    if (tid < BROWS) {
        int excl = sh[tid] - v;
        cur[tid] = excl;
        if (row0 + tid < n_nodes) rp[row0 + tid] = bb + excl;   // coalesced rp
    }
    __syncthreads();
    for (int p = bb + tid; p < be; p += 512) {
        int2 e = bin[p];
        int rl = e.x >> COLBITS;
        int k = atomicAdd(&cur[rl], 1);
        sce[bb + k] = make_int2(e.x & ((1 << COLBITS) - 1), e.y);
    }
}

// One wave per output row, lane = dim. fp16 gathers (2 B/lane), fp32 accum,
// 8-deep batched loads into 4 rotating accumulators.
__global__ __launch_bounds__(256) void spmm_h_kernel(
        const int* __restrict__ rp, const int2* __restrict__ sce,
        const __half* __restrict__ xin, __half* __restrict__ xnxt,
        int n_nodes) {
    int wid = (int)(((long long)blockIdx.x * blockDim.x + threadIdx.x) >> 6);
    int lane = threadIdx.x & 63;
    if (wid >= n_nodes) return;
    int beg = __builtin_amdgcn_readfirstlane(rp[wid]);
    int end = __builtin_amdgcn_readfirstlane(rp[wid + 1]);
    const unsigned long long* __restrict__ sceq = (const unsigned long long*)sce;
    float s0 = 0.f, s1 = 0.f, s2 = 0.f, s3 = 0.f;
    int p = beg;
    for (; p + 8 <= end; p += 8) {
        unsigned long long u0 = __builtin_nontemporal_load(sceq + p + 0);
        unsigned long long u1 = __builtin_nontemporal_load(sceq + p + 1);
        unsigned long long u2 = __builtin_nontemporal_load(sceq + p + 2);
        unsigned long long u3 = __builtin_nontemporal_load(sceq + p + 3);
        unsigned long long u4 = __builtin_nontemporal_load(sceq + p + 4);
        unsigned long long u5 = __builtin_nontemporal_load(sceq + p + 5);
        unsigned long long u6 = __builtin_nontemporal_load(sceq + p + 6);
        unsigned long long u7 = __builtin_nontemporal_load(sceq + p + 7);
        float g0 = __half2float(xin[((int)(unsigned)u0) * EMB_C + lane]);
        float g1 = __half2float(xin[((int)(unsigned)u1) * EMB_C + lane]);
        float g2 = __half2float(xin[((int)(unsigned)u2) * EMB_C + lane]);
        float g3 = __half2float(xin[((int)(unsigned)u3) * EMB_C + lane]);
        float g4 = __half2float(xin[((int)(unsigned)u4) * EMB_C + lane]);
        float g5 = __half2float(xin[((int)(unsigned)u5) * EMB_C + lane]);
        float g6 = __half2float(xin[((int)(unsigned)u6) * EMB_C + lane]);
        float g7 = __half2float(xin[((int)(unsigned)u7) * EMB_C + lane]);
        s0 = fmaf(__int_as_float((int)(u0 >> 32)), g0, s0);
        s1 = fmaf(__int_as_float((int)(u1 >> 32)), g1, s1);
        s2 = fmaf(__int_as_float((int)(u2 >> 32)), g2, s2);
        s3 = fmaf(__int_as_float((int)(u3 >> 32)), g3, s3);
        s0 = fmaf(__int_as_float((int)(u4 >> 32)), g4, s0);
        s1 = fmaf(__int_as_float((int)(u5 >> 32)), g5, s1);
        s2 = fmaf(__int_as_float((int)(u6 >> 32)), g6, s2);
        s3 = fmaf(__int_as_float((int)(u7 >> 32)), g7, s3);
    }
    for (; p + 4 <= end; p += 4) {
        unsigned long long u0 = __builtin_nontemporal_load(sceq + p + 0);
        unsigned long long u1 = __builtin_nontemporal_load(sceq + p + 1);
        unsigned long long u2 = __builtin_nontemporal_load(sceq + p + 2);
        unsigned long long u3 = __builtin_nontemporal_load(sceq + p + 3);
        float g0 = __half2float(xin[((int)(unsigned)u0) * EMB_C + lane]);
        float g1 = __half2float(xin[((int)(unsigned)u1) * EMB_C + lane]);
        float g2 = __half2float(xin[((int)(unsigned)u2) * EMB_C + lane]);
        float g3 = __half2float(xin[((int)(unsigned)u3) * EMB_C + lane]);
        s0 = fmaf(__int_as_float((int)(u0 >> 32)), g0, s0);
        s1 = fmaf(__int_as_float((int)(u1 >> 32)), g1, s1);
        s2 = fmaf(__int_as_float((int)(u2 >> 32)), g2, s2);
        s3 = fmaf(__int_as_float((int)(u3 >> 32)), g3, s3);
    }
    for (; p < end; ++p) {
        unsigned long long u = __builtin_nontemporal_load(sceq + p);
        s0 = fmaf(__int_as_float((int)(u >> 32)),
                  __half2float(xin[((int)(unsigned)u) * EMB_C + lane]), s0);
    }
    float s = (s0 + s1) + (s2 + s3);
    unsigned short hs = __half_as_ushort(__float2half(s));
    __builtin_nontemporal_store(hs, (unsigned short*)(xnxt + wid * EMB_C + lane));
}

// out = 0.25 * (x0+x1+x2+x3)[row] at gathered rows (fp16 -> fp32 sum).
__global__ __launch_bounds__(256) void gather_h_kernel(
        const __half* __restrict__ p0, const __half* __restrict__ p1,
        const __half* __restrict__ p2, const __half* __restrict__ p3,
        const int* __restrict__ users, const int* __restrict__ pos,
        const int* __restrict__ neg, float* __restrict__ out,
        int batch, float scale) {
    long long gid = (long long)blockIdx.x * blockDim.x + threadIdx.x;
    long long per = (long long)batch * EMB_C;
    if (gid >= 3 * per) return;
    int which = (int)(gid / per);
    long long rem = gid - (long long)which * per;
    int b = (int)(rem >> 6);
    int d = (int)(rem & 63);
    long long row;
    if (which == 0)      row = users[b];
    else if (which == 1) row = (long long)N_USER_C + pos[b];
    else                 row = (long long)N_USER_C + neg[b];
    long long idx = row * EMB_C + d;
    out[gid] = scale * (__half2float(p0[idx]) + __half2float(p1[idx]) +
                        __half2float(p2[idx]) + __half2float(p3[idx]));
}

// ======================= fallback (atomic) kernels ========================

__global__ __launch_bounds__(256) void fill_kernel(
        const float4* __restrict__ ue, const float4* __restrict__ ie,
        float4* __restrict__ x0, float4* __restrict__ a,
        float4* __restrict__ b, long long u4, long long t4) {
    long long i = (long long)blockIdx.x * blockDim.x + threadIdx.x;
    if (i >= t4) return;
    float4 v = (i < u4) ? ue[i] : ie[i - u4];
    x0[i] = v;
    a[i] = v;
    b[i] = make_float4(0.f, 0.f, 0.f, 0.f);
}

__global__ __launch_bounds__(256) void spmm_kernel(
        const float* __restrict__ vals, const int* __restrict__ rows,
        const int* __restrict__ cols, const float* __restrict__ xin,
        float* __restrict__ xout, int nnz) {
    long long gid = (long long)blockIdx.x * blockDim.x + threadIdx.x;
    int e = (int)(gid >> 6);
    int d = (int)(gid & 63);
    if (e >= nnz) return;
    unsafeAtomicAdd(&xout[(long long)rows[e] * EMB_C + d],
                    vals[e] * xin[(long long)cols[e] * EMB_C + d]);
}

__global__ __launch_bounds__(256) void acczero_kernel(
        float4* __restrict__ acc, const float4* __restrict__ src,
        float4* __restrict__ tozero, long long n4) {
    long long i = (long long)blockIdx.x * blockDim.x + threadIdx.x;
    if (i >= n4) return;
    float4 a = acc[i], s = src[i];
    a.x += s.x; a.y += s.y; a.z += s.z; a.w += s.w;
    acc[i] = a;
    if (tozero) tozero[i] = make_float4(0.f, 0.f, 0.f, 0.f);
}

__global__ __launch_bounds__(256) void gather_f_kernel(
        const float* __restrict__ acc,
        const int* __restrict__ users, const int* __restrict__ pos,
        const int* __restrict__ neg, float* __restrict__ out,
        int batch, float scale) {
    long long gid = (long long)blockIdx.x * blockDim.x + threadIdx.x;
    long long per = (long long)batch * EMB_C;
    if (gid >= 3 * per) return;
    int which = (int)(gid / per);
    long long rem = gid - (long long)which * per;
    int b = (int)(rem >> 6);
    int d = (int)(rem & 63);
    long long row;
    if (which == 0)      row = users[b];
    else if (which == 1) row = (long long)N_USER_C + pos[b];
    else                 row = (long long)N_USER_C + neg[b];
    out[gid] = scale * acc[row * EMB_C + d];
}

// ================================ driver ==================================

extern "C" void kernel_launch(void* const* d_in, const int* in_sizes, int n_in,
                              void* d_out, int out_size, void* d_ws, size_t ws_size,
                              hipStream_t stream) {
    const float* ue    = (const float*)d_in[0];
    const float* ie    = (const float*)d_in[1];
    const float* vals  = (const float*)d_in[2];
    const int*   rows  = (const int*)d_in[3];
    const int*   cols  = (const int*)d_in[4];
    const int*   users = (const int*)d_in[5];
    const int*   pos   = (const int*)d_in[6];
    const int*   neg   = (const int*)d_in[7];
    float* out = (float*)d_out;

    const int nnz   = in_sizes[2];
    const int batch = in_sizes[5];
    const long long uelems = (long long)in_sizes[0];
    const long long total  = uelems + (long long)in_sizes[1];  // n_nodes * EMB
    const int n_nodes = (int)(total / EMB_C);
    const long long u4 = uelems / 4, t4 = total / 4;

    const int T = 256;
    const int fill_blocks = (int)((t4 + T - 1) / T);
    const int gath_blocks = (int)((3LL * batch * EMB_C + T - 1) / T);
    const int spmm_blocks = (int)(((long long)n_nodes * EMB_C + T - 1) / T);
    const int nb = (n_nodes + BROWS - 1) / BROWS;

    // fp16 layout (bytes): x0..x3 | rp(RN*4) | btot(1024*4) | bbase(1024*4) |
    // ghist(NC*NBMAX*4) | sce(nnz*8) | bin(nnz*8)
    const long long RN = ((n_nodes + 1 + 15) / 16) * 16;
    const size_t xbytes = (size_t)total * 2;
    const size_t fixed = 4 * xbytes + (size_t)(RN + 2048) * 4 + (size_t)nnz * 16;
    const bool fits_nb = (nb <= NBMAX) && (n_nodes <= (1 << COLBITS));

    // Prefer small chunks (occupancy) if ghist fits; else fall back to 8192.
    int csz = 2048;
    int NC = (nnz + csz - 1) / csz;
    if (!fits_nb || ws_size < fixed + (size_t)NC * NBMAX * 4) {
        csz = 8192;
        NC = (nnz + csz - 1) / csz;
    }
    const size_t needH = fixed + (size_t)NC * NBMAX * 4;

    char* wb = (char*)d_ws;

    if (fits_nb && ws_size >= needH) {
        __half* x0 = (__half*)wb;
        __half* x1 = (__half*)(wb + xbytes);
        __half* x2 = (__half*)(wb + 2 * xbytes);
        __half* x3 = (__half*)(wb + 3 * xbytes);
        int*   rp    = (int*)(wb + 4 * xbytes);
        int*   btot  = rp + RN;
        int*   bbase = btot + 1024;
        int*   ghist = bbase + 1024;
        int2*  sce   = (int2*)(ghist + (size_t)NC * NBMAX);
        int2*  bin   = sce + nnz;

        fill_h_kernel<<<fill_blocks, T, 0, stream>>>(
            (const float4*)ue, (const float4*)ie, (ushort4*)x0, u4, t4);

        chunkhist_kernel<<<NC, T, 0, stream>>>(rows, ghist, nnz, nb, csz);
        colscan_kernel<<<nb, T, 0, stream>>>(ghist, btot, NC, nb);
        bucketscan_kernel<<<1, 1024, 0, stream>>>(btot, bbase, rp, nb, nnz, n_nodes);
        binscatter2_kernel<<<NC, T, 0, stream>>>(rows, cols, vals, ghist, bbase,
                                                 bin, nnz, nb, csz);
        finscatter_kernel<<<nb, 512, 0, stream>>>(bin, bbase, rp, sce, n_nodes);

        spmm_h_kernel<<<spmm_blocks, T, 0, stream>>>(rp, sce, x0, x1, n_nodes);
        spmm_h_kernel<<<spmm_blocks, T, 0, stream>>>(rp, sce, x1, x2, n_nodes);
        spmm_h_kernel<<<spmm_blocks, T, 0, stream>>>(rp, sce, x2, x3, n_nodes);

        gather_h_kernel<<<gath_blocks, T, 0, stream>>>(
            x0, x1, x2, x3, users, pos, neg, out, batch, 0.25f);
    } else {
        // ---- Tier C: 3-buffer fp32 atomic fallback ----
        float* cur = (float*)wb;
        float* nxt = cur + total;
        float* acc = nxt + total;
        fill_kernel<<<fill_blocks, T, 0, stream>>>(
            (const float4*)ue, (const float4*)ie,
            (float4*)cur, (float4*)acc, (float4*)nxt, u4, t4);
        const int espmm_blocks = (int)(((long long)nnz * EMB_C + T - 1) / T);
        for (int l = 0; l < 3; ++l) {
            spmm_kernel<<<espmm_blocks, T, 0, stream>>>(vals, rows, cols, cur, nxt, nnz);
            float4* tz = (l < 2) ? (float4*)cur : nullptr;
            acczero_kernel<<<fill_blocks, T, 0, stream>>>(
                (float4*)acc, (const float4*)nxt, tz, t4);
            float* t = cur; cur = nxt; nxt = t;
        }
        gather_f_kernel<<<gath_blocks, T, 0, stream>>>(
            acc, users, pos, neg, out, batch, 0.0625f);
    }
}